// Round 1
// baseline (309.154 us; speedup 1.0000x reference)
//
#include <hip/hip_runtime.h>
#include <math.h>

// Problem dims (fixed by reference)
constexpr int Lz  = 4;
constexpr int Bb  = 128;
constexpr int INs = 512;
constexpr int CTX = 512;
constexpr int STd = 512;
constexpr int Dd  = 1536;   // IN + CTX + ST
constexpr int Rr  = 256;
constexpr int Cc  = 256;

constexpr int BM = 32, BN = 32, BK = 32;

__device__ __forceinline__ float sigmoidf(float v) { return 1.0f / (1.0f + expf(-v)); }

// ---------------- Phase 1: gated state update ----------------
// gi = [x, c, h[l]]  (B x D);  phi/alpha/beta = gi @ W^T + b
// h_new = sigmoid(alpha) * tanh(phi) + sigmoid(beta) * h
__global__ __launch_bounds__(256) void k_gate(
    const float* __restrict__ x, const float* __restrict__ c, const float* __restrict__ h,
    const float* __restrict__ phi_w, const float* __restrict__ phi_b,
    const float* __restrict__ alpha_w, const float* __restrict__ alpha_b,
    const float* __restrict__ beta_w, const float* __restrict__ beta_b,
    float* __restrict__ h_new)
{
    __shared__ float As[BK][BM + 1];
    __shared__ float Ws[3][BK][BN + 1];

    const int l  = blockIdx.z;
    const int b0 = blockIdx.y * BM;
    const int o0 = blockIdx.x * BN;
    const int tx = threadIdx.x, ty = threadIdx.y;
    const int tid = ty * 16 + tx;

    const float* wptr[3] = { phi_w, alpha_w, beta_w };

    float acc[3][2][2] = {};

    for (int kk = 0; kk < Dd; kk += BK) {
        // A tile: gi[b0+m][kk+k]   (k fastest in tid -> coalesced global d)
        #pragma unroll
        for (int it = 0; it < (BM * BK) / 256; ++it) {
            int idx = it * 256 + tid;
            int k = idx & (BK - 1);
            int m = idx >> 5;            // BK == 32
            int b = b0 + m, d = kk + k;
            float val;
            if (d < INs)            val = x[b * INs + d];
            else if (d < INs + CTX) val = c[b * CTX + (d - INs)];
            else                    val = h[(l * Bb + b) * STd + (d - INs - CTX)];
            As[k][m] = val;
        }
        // W tiles (3 arrays)
        #pragma unroll
        for (int arr = 0; arr < 3; ++arr) {
            const float* W = wptr[arr];
            #pragma unroll
            for (int it = 0; it < (BN * BK) / 256; ++it) {
                int idx = it * 256 + tid;
                int k = idx & (BK - 1);
                int n = idx >> 5;
                Ws[arr][k][n] = W[(l * STd + o0 + n) * Dd + kk + k];
            }
        }
        __syncthreads();

        #pragma unroll
        for (int k = 0; k < BK; ++k) {
            float a0 = As[k][tx * 2 + 0];
            float a1 = As[k][tx * 2 + 1];
            #pragma unroll
            for (int arr = 0; arr < 3; ++arr) {
                float w0 = Ws[arr][k][ty * 2 + 0];
                float w1 = Ws[arr][k][ty * 2 + 1];
                acc[arr][0][0] += a0 * w0;
                acc[arr][0][1] += a0 * w1;
                acc[arr][1][0] += a1 * w0;
                acc[arr][1][1] += a1 * w1;
            }
        }
        __syncthreads();
    }

    #pragma unroll
    for (int i = 0; i < 2; ++i) {
        #pragma unroll
        for (int j = 0; j < 2; ++j) {
            int b = b0 + tx * 2 + i;
            int o = o0 + ty * 2 + j;
            float phi = acc[0][i][j] + phi_b[l * STd + o];
            float al  = sigmoidf(acc[1][i][j] + alpha_b[l * STd + o]);
            float be  = sigmoidf(acc[2][i][j] + beta_b[l * STd + o]);
            float ho  = h[(l * Bb + b) * STd + o];
            h_new[(l * Bb + b) * STd + o] = al * tanhf(phi) + be * ho;
        }
    }
}

// ---------------- Phase 2: u, v projections ----------------
// wv = [h_new, x, c];  u = wv @ u_w^T + u_b (R), v = wv @ v_w^T + v_b (C)
__global__ __launch_bounds__(256) void k_uv(
    const float* __restrict__ x, const float* __restrict__ c,
    const float* __restrict__ h_new,
    const float* __restrict__ u_w, const float* __restrict__ u_b,
    const float* __restrict__ v_w, const float* __restrict__ v_b,
    float* __restrict__ u_out, float* __restrict__ v_out)
{
    __shared__ float As[BK][BM + 1];
    __shared__ float Ws[BK][BN + 1];

    const int l  = blockIdx.z;
    const int b0 = blockIdx.y * BM;
    const int n0 = blockIdx.x * BN;      // 0..511 over [u | v]
    const int tx = threadIdx.x, ty = threadIdx.y;
    const int tid = ty * 16 + tx;

    const float* W;  const float* bias;  float* out;  int nbase;
    if (n0 < Rr) { W = u_w; bias = u_b; out = u_out; nbase = n0; }
    else         { W = v_w; bias = v_b; out = v_out; nbase = n0 - Rr; }

    float acc[2][2] = {};

    for (int kk = 0; kk < Dd; kk += BK) {
        #pragma unroll
        for (int it = 0; it < (BM * BK) / 256; ++it) {
            int idx = it * 256 + tid;
            int k = idx & (BK - 1);
            int m = idx >> 5;
            int b = b0 + m, d = kk + k;
            float val;
            if (d < STd)             val = h_new[(l * Bb + b) * STd + d];
            else if (d < STd + INs)  val = x[b * INs + (d - STd)];
            else                     val = c[b * CTX + (d - STd - INs)];
            As[k][m] = val;
        }
        #pragma unroll
        for (int it = 0; it < (BN * BK) / 256; ++it) {
            int idx = it * 256 + tid;
            int k = idx & (BK - 1);
            int n = idx >> 5;
            Ws[k][n] = W[(l * Rr + nbase + n) * Dd + kk + k];  // Rr == Cc
        }
        __syncthreads();

        #pragma unroll
        for (int k = 0; k < BK; ++k) {
            float a0 = As[k][tx * 2 + 0];
            float a1 = As[k][tx * 2 + 1];
            float w0 = Ws[k][ty * 2 + 0];
            float w1 = Ws[k][ty * 2 + 1];
            acc[0][0] += a0 * w0;
            acc[0][1] += a0 * w1;
            acc[1][0] += a1 * w0;
            acc[1][1] += a1 * w1;
        }
        __syncthreads();
    }

    #pragma unroll
    for (int i = 0; i < 2; ++i) {
        #pragma unroll
        for (int j = 0; j < 2; ++j) {
            int b = b0 + tx * 2 + i;
            int n = nbase + ty * 2 + j;
            out[(l * Bb + b) * Rr + n] = acc[i][j] + bias[l * Rr + n];
        }
    }
}

// ---------------- Phase 3: EMA memory write (level-fused, float4) ----------------
__global__ __launch_bounds__(256) void k_mupd(
    const float4* __restrict__ M, const float* __restrict__ u, const float4* __restrict__ v,
    const float* __restrict__ gl, const float* __restrict__ el,
    float4* __restrict__ Mout)
{
    const int t = blockIdx.x * 256 + threadIdx.x;   // over B*R*C/4
    const int c4 = t & 63;              // C/4 = 64
    const int r  = (t >> 6) & 255;
    const int b  = t >> 14;
    constexpr int strideL = Bb * Rr * Cc / 4;       // float4 per level

    float4 m[4]; float uu[4]; float4 vv[4];
    #pragma unroll
    for (int l = 0; l < 4; ++l) {
        m[l]  = M[l * strideL + t];
        uu[l] = u[(l * Bb + b) * Rr + r];
        vv[l] = v[(l * Bb + b) * (Cc / 4) + c4];
    }

    #pragma unroll
    for (int l = 0; l < 4; ++l) {
        const int lu = (l == 0) ? 0 : l - 1;
        const int ld = (l == 3) ? 3 : l + 1;
        const float g = sigmoidf(gl[l]);
        const float e = sigmoidf(el[l]);
        float4 o;
        o.x = (1.0f - g) * m[l].x + g * 0.5f * (m[lu].x + m[ld].x) + e * uu[l] * vv[l].x;
        o.y = (1.0f - g) * m[l].y + g * 0.5f * (m[lu].y + m[ld].y) + e * uu[l] * vv[l].y;
        o.z = (1.0f - g) * m[l].z + g * 0.5f * (m[lu].z + m[ld].z) + e * uu[l] * vv[l].z;
        o.w = (1.0f - g) * m[l].w + g * 0.5f * (m[lu].w + m[ld].w) + e * uu[l] * vv[l].w;
        Mout[l * strideL + t] = o;
    }
}

extern "C" void kernel_launch(void* const* d_in, const int* in_sizes, int n_in,
                              void* d_out, int out_size, void* d_ws, size_t ws_size,
                              hipStream_t stream) {
    const float* x       = (const float*)d_in[0];
    const float* c       = (const float*)d_in[1];
    const float* h       = (const float*)d_in[2];
    const float* M       = (const float*)d_in[3];
    const float* phi_w   = (const float*)d_in[4];
    const float* phi_b   = (const float*)d_in[5];
    const float* alpha_w = (const float*)d_in[6];
    const float* alpha_b = (const float*)d_in[7];
    const float* beta_w  = (const float*)d_in[8];
    const float* beta_b  = (const float*)d_in[9];
    const float* u_w     = (const float*)d_in[10];
    const float* u_b     = (const float*)d_in[11];
    const float* v_w     = (const float*)d_in[12];
    const float* v_b     = (const float*)d_in[13];
    const float* gl      = (const float*)d_in[14];
    const float* el      = (const float*)d_in[15];

    float* out   = (float*)d_out;
    float* h_new = out;                          // L*B*ST = 262144
    float* M_new = out + Lz * Bb * STd;          // L*B*R*C

    float* u = (float*)d_ws;                     // L*B*R
    float* v = u + Lz * Bb * Rr;                 // L*B*C

    dim3 blk(16, 16);
    // phase 1: 16 n-tiles (ST/32), 4 m-tiles (B/32), 4 levels
    k_gate<<<dim3(STd / BN, Bb / BM, Lz), blk, 0, stream>>>(
        x, c, h, phi_w, phi_b, alpha_w, alpha_b, beta_w, beta_b, h_new);
    // phase 2: 16 n-tiles ((R+C)/32), 4 m-tiles, 4 levels
    k_uv<<<dim3((Rr + Cc) / BN, Bb / BM, Lz), blk, 0, stream>>>(
        x, c, h_new, u_w, u_b, v_w, v_b, u, v);
    // phase 3: B*R*C/4 float4 sites, level-fused
    k_mupd<<<(Bb * Rr * Cc / 4) / 256, 256, 0, stream>>>(
        (const float4*)M, u, (const float4*)v, gl, el, (float4*)M_new);
}

// Round 2
// 118.915 us; speedup vs baseline: 2.5998x; 2.5998x over previous
//
#include <hip/hip_runtime.h>
#include <math.h>
#include <stdint.h>

// Problem dims (fixed by reference)
constexpr int Lz  = 4;
constexpr int Bb  = 128;
constexpr int STd = 512;
constexpr int Dd  = 1536;   // IN + CTX + ST
constexpr int Rr  = 256;
constexpr int Cc  = 256;

typedef __bf16 bf16x8 __attribute__((ext_vector_type(8)));
typedef float  f32x4  __attribute__((ext_vector_type(4)));

__device__ __forceinline__ float sigmoidf_(float v) { return 1.0f / (1.0f + expf(-v)); }

// pack two f32 -> dword of 2 bf16 (round-half-up via +0x8000, then v_perm high halves)
__device__ __forceinline__ uint32_t pkbf16(float a, float b) {
    uint32_t ua = __float_as_uint(a) + 0x8000u;
    uint32_t ub = __float_as_uint(b) + 0x8000u;
    return __builtin_amdgcn_perm(ub, ua, 0x07060302u);  // lo16=bf16(a), hi16=bf16(b)
}
__device__ __forceinline__ uint4 cvt8(const float4 lo, const float4 hi) {
    uint4 r;
    r.x = pkbf16(lo.x, lo.y); r.y = pkbf16(lo.z, lo.w);
    r.z = pkbf16(hi.x, hi.y); r.w = pkbf16(hi.z, hi.w);
    return r;
}

// ============================================================================
// Phase 1: gated state update via bf16 MFMA.
// out tile: BM=32 (b) x BN=32 (o), all 3 weight arrays per block (A-frag reuse).
// LDS fragment-ordered: slot byte = ((rowblk*2+kstep)*64 + lane)*16, zero-conflict
// linear ds_read_b128/ds_write_b128. Reg-staged prefetch double-buffer.
// MFMA A-frag: row=lane&15, k=(lane>>4)*8+e ; B-frag: col=lane&15, same k.
// C/D: col=lane&15, row=(lane>>4)*4+reg.
// ============================================================================
__global__ __launch_bounds__(256) void k_gate(
    const float* __restrict__ x, const float* __restrict__ c, const float* __restrict__ h,
    const float* __restrict__ phi_w, const float* __restrict__ phi_b,
    const float* __restrict__ alpha_w, const float* __restrict__ alpha_b,
    const float* __restrict__ beta_w, const float* __restrict__ beta_b,
    float* __restrict__ h_new)
{
    __shared__ uint32_t lds[4096];  // A: [0,1024) uints ; B arr a: [1024*(1+a), +1024)

    const int l  = blockIdx.z;
    const int b0 = blockIdx.y * 32;
    const int o0 = blockIdx.x * 32;
    const int t  = threadIdx.x;

    // staging slot -> (row, kd) this thread stages (8 consecutive d)
    const int rowblk = t >> 7;
    const int kstep  = (t >> 6) & 1;
    const int ls     = t & 63;
    const int mrow   = (rowblk << 4) | (ls & 15);
    const int kd     = kstep * 32 + ((ls >> 4) << 3);
    const int slot_u = t * 4;                       // uint idx of 16B slot

    const float* wrow0 = phi_w   + (size_t)(l * STd + o0 + mrow) * Dd + kd;
    const float* wrow1 = alpha_w + (size_t)(l * STd + o0 + mrow) * Dd + kd;
    const float* wrow2 = beta_w  + (size_t)(l * STd + o0 + mrow) * Dd + kd;

    // A source bases (gi = [x | c | h[l]]), all row-stride 512; tile never crosses seg
    const float* abase0 = x + (size_t)(b0 + mrow) * 512 + kd;
    const float* abase1 = c + (size_t)(b0 + mrow) * 512 + kd - 512;
    const float* abase2 = h + (size_t)(l * Bb + b0 + mrow) * 512 + kd - 1024;

    float4 pa0, pa1;
    float4 pb[3][2];

    auto issue = [&](int kk) {
        const float* p = (kk < 512 ? abase0 : (kk < 1024 ? abase1 : abase2)) + kk;
        pa0 = *(const float4*)p;
        pa1 = *(const float4*)(p + 4);
        pb[0][0] = *(const float4*)(wrow0 + kk); pb[0][1] = *(const float4*)(wrow0 + kk + 4);
        pb[1][0] = *(const float4*)(wrow1 + kk); pb[1][1] = *(const float4*)(wrow1 + kk + 4);
        pb[2][0] = *(const float4*)(wrow2 + kk); pb[2][1] = *(const float4*)(wrow2 + kk + 4);
    };

    const int lane = t & 63;
    const int w    = t >> 6;
    const int m    = w >> 1;      // A 16-row block
    const int n    = w & 1;       // B 16-col block

    f32x4 acc[3] = {};

    issue(0);
    for (int kk = 0; kk < Dd; kk += 64) {
        *(uint4*)&lds[slot_u] = cvt8(pa0, pa1);
        *(uint4*)&lds[1024 + slot_u] = cvt8(pb[0][0], pb[0][1]);
        *(uint4*)&lds[2048 + slot_u] = cvt8(pb[1][0], pb[1][1]);
        *(uint4*)&lds[3072 + slot_u] = cvt8(pb[2][0], pb[2][1]);
        __syncthreads();
        if (kk + 64 < Dd) issue(kk + 64);   // in-flight under MFMA below
        #pragma unroll
        for (int ks = 0; ks < 2; ++ks) {
            bf16x8 af = *(bf16x8*)&lds[((m * 2 + ks) * 64 + lane) * 4];
            bf16x8 bf0 = *(bf16x8*)&lds[1024 + ((n * 2 + ks) * 64 + lane) * 4];
            bf16x8 bf1 = *(bf16x8*)&lds[2048 + ((n * 2 + ks) * 64 + lane) * 4];
            bf16x8 bf2 = *(bf16x8*)&lds[3072 + ((n * 2 + ks) * 64 + lane) * 4];
            acc[0] = __builtin_amdgcn_mfma_f32_16x16x32_bf16(af, bf0, acc[0], 0, 0, 0);
            acc[1] = __builtin_amdgcn_mfma_f32_16x16x32_bf16(af, bf1, acc[1], 0, 0, 0);
            acc[2] = __builtin_amdgcn_mfma_f32_16x16x32_bf16(af, bf2, acc[2], 0, 0, 0);
        }
        __syncthreads();
    }

    // epilogue: h_new = sigmoid(alpha)*tanh(phi) + sigmoid(beta)*h
    const int bout = b0 + m * 16 + (lane >> 4) * 4;
    const int ocol = o0 + n * 16 + (lane & 15);
    const float pbias = phi_b[l * STd + ocol];
    const float abias = alpha_b[l * STd + ocol];
    const float bbias = beta_b[l * STd + ocol];
    #pragma unroll
    for (int r = 0; r < 4; ++r) {
        const int b = bout + r;
        float phi = acc[0][r] + pbias;
        float al  = sigmoidf_(acc[1][r] + abias);
        float be  = sigmoidf_(acc[2][r] + bbias);
        float ho  = h[(size_t)(l * Bb + b) * STd + ocol];
        h_new[(size_t)(l * Bb + b) * STd + ocol] = al * tanhf(phi) + be * ho;
    }
}

// ============================================================================
// Phase 2: u,v projections via bf16 MFMA (same structure, single weight array)
// wv = [h_new | x | c]
// ============================================================================
__global__ __launch_bounds__(256) void k_uv(
    const float* __restrict__ x, const float* __restrict__ c,
    const float* __restrict__ h_new,
    const float* __restrict__ u_w, const float* __restrict__ u_b,
    const float* __restrict__ v_w, const float* __restrict__ v_b,
    float* __restrict__ u_out, float* __restrict__ v_out)
{
    __shared__ uint32_t lds[2048];  // A: [0,1024) ; B: [1024,2048)

    const int l   = blockIdx.z;
    const int b0  = blockIdx.y * 32;
    const int n0g = blockIdx.x * 32;   // 0..511 over [u | v]
    const int t   = threadIdx.x;

    const float* W; const float* bias; float* out; int o_base;
    if (n0g < Rr) { W = u_w; bias = u_b; out = u_out; o_base = n0g; }
    else          { W = v_w; bias = v_b; out = v_out; o_base = n0g - Rr; }

    const int rowblk = t >> 7;
    const int kstep  = (t >> 6) & 1;
    const int ls     = t & 63;
    const int mrow   = (rowblk << 4) | (ls & 15);
    const int kd     = kstep * 32 + ((ls >> 4) << 3);
    const int slot_u = t * 4;

    const float* wrow = W + (size_t)(l * Rr + o_base + mrow) * Dd + kd;
    const float* abase0 = h_new + (size_t)(l * Bb + b0 + mrow) * 512 + kd;
    const float* abase1 = x + (size_t)(b0 + mrow) * 512 + kd - 512;
    const float* abase2 = c + (size_t)(b0 + mrow) * 512 + kd - 1024;

    float4 pa0, pa1, pb0, pb1;
    auto issue = [&](int kk) {
        const float* p = (kk < 512 ? abase0 : (kk < 1024 ? abase1 : abase2)) + kk;
        pa0 = *(const float4*)p;
        pa1 = *(const float4*)(p + 4);
        pb0 = *(const float4*)(wrow + kk);
        pb1 = *(const float4*)(wrow + kk + 4);
    };

    const int lane = t & 63;
    const int w    = t >> 6;
    const int m    = w >> 1;
    const int n    = w & 1;

    f32x4 acc = {};

    issue(0);
    for (int kk = 0; kk < Dd; kk += 64) {
        *(uint4*)&lds[slot_u]        = cvt8(pa0, pa1);
        *(uint4*)&lds[1024 + slot_u] = cvt8(pb0, pb1);
        __syncthreads();
        if (kk + 64 < Dd) issue(kk + 64);
        #pragma unroll
        for (int ks = 0; ks < 2; ++ks) {
            bf16x8 af = *(bf16x8*)&lds[((m * 2 + ks) * 64 + lane) * 4];
            bf16x8 bf = *(bf16x8*)&lds[1024 + ((n * 2 + ks) * 64 + lane) * 4];
            acc = __builtin_amdgcn_mfma_f32_16x16x32_bf16(af, bf, acc, 0, 0, 0);
        }
        __syncthreads();
    }

    const int bout = b0 + m * 16 + (lane >> 4) * 4;
    const int ocol = o_base + n * 16 + (lane & 15);
    const float bv = bias[l * Rr + ocol];
    #pragma unroll
    for (int r = 0; r < 4; ++r) {
        out[(size_t)(l * Bb + bout + r) * Rr + ocol] = acc[r] + bv;
    }
}

// ============================================================================
// Phase 3: EMA memory write (level-fused, float4) — unchanged (near-roofline)
// ============================================================================
__global__ __launch_bounds__(256) void k_mupd(
    const float4* __restrict__ M, const float* __restrict__ u, const float4* __restrict__ v,
    const float* __restrict__ gl, const float* __restrict__ el,
    float4* __restrict__ Mout)
{
    const int t = blockIdx.x * 256 + threadIdx.x;   // over B*R*C/4
    const int c4 = t & 63;              // C/4 = 64
    const int r  = (t >> 6) & 255;
    const int b  = t >> 14;
    constexpr int strideL = Bb * Rr * Cc / 4;

    float4 m[4]; float uu[4]; float4 vv[4];
    #pragma unroll
    for (int l = 0; l < 4; ++l) {
        m[l]  = M[l * strideL + t];
        uu[l] = u[(l * Bb + b) * Rr + r];
        vv[l] = v[(l * Bb + b) * (Cc / 4) + c4];
    }

    #pragma unroll
    for (int l = 0; l < 4; ++l) {
        const int lu = (l == 0) ? 0 : l - 1;
        const int ld = (l == 3) ? 3 : l + 1;
        const float g = sigmoidf_(gl[l]);
        const float e = sigmoidf_(el[l]);
        float4 o;
        o.x = (1.0f - g) * m[l].x + g * 0.5f * (m[lu].x + m[ld].x) + e * uu[l] * vv[l].x;
        o.y = (1.0f - g) * m[l].y + g * 0.5f * (m[lu].y + m[ld].y) + e * uu[l] * vv[l].y;
        o.z = (1.0f - g) * m[l].z + g * 0.5f * (m[lu].z + m[ld].z) + e * uu[l] * vv[l].z;
        o.w = (1.0f - g) * m[l].w + g * 0.5f * (m[lu].w + m[ld].w) + e * uu[l] * vv[l].w;
        Mout[l * strideL + t] = o;
    }
}

extern "C" void kernel_launch(void* const* d_in, const int* in_sizes, int n_in,
                              void* d_out, int out_size, void* d_ws, size_t ws_size,
                              hipStream_t stream) {
    const float* x       = (const float*)d_in[0];
    const float* c       = (const float*)d_in[1];
    const float* h       = (const float*)d_in[2];
    const float* M       = (const float*)d_in[3];
    const float* phi_w   = (const float*)d_in[4];
    const float* phi_b   = (const float*)d_in[5];
    const float* alpha_w = (const float*)d_in[6];
    const float* alpha_b = (const float*)d_in[7];
    const float* beta_w  = (const float*)d_in[8];
    const float* beta_b  = (const float*)d_in[9];
    const float* u_w     = (const float*)d_in[10];
    const float* u_b     = (const float*)d_in[11];
    const float* v_w     = (const float*)d_in[12];
    const float* v_b     = (const float*)d_in[13];
    const float* gl      = (const float*)d_in[14];
    const float* el      = (const float*)d_in[15];

    float* out   = (float*)d_out;
    float* h_new = out;                          // L*B*ST
    float* M_new = out + Lz * Bb * STd;          // L*B*R*C

    float* u = (float*)d_ws;                     // L*B*R
    float* v = u + Lz * Bb * Rr;                 // L*B*C

    // phase 1: MFMA gate — grid (o-tiles 16, b-tiles 4, levels 4) = 256 blocks
    k_gate<<<dim3(STd / 32, Bb / 32, Lz), 256, 0, stream>>>(
        x, c, h, phi_w, phi_b, alpha_w, alpha_b, beta_w, beta_b, h_new);
    // phase 2: MFMA u/v — grid ((R+C)/32 = 16, 4, 4) = 256 blocks
    k_uv<<<dim3((Rr + Cc) / 32, Bb / 32, Lz), 256, 0, stream>>>(
        x, c, h_new, u_w, u_b, v_w, v_b, u, v);
    // phase 3: streaming M update
    k_mupd<<<(Bb * Rr * Cc / 4) / 256, 256, 0, stream>>>(
        (const float4*)M, u, (const float4*)v, gl, el, (float4*)M_new);
}

// Round 3
// 90.935 us; speedup vs baseline: 3.3997x; 1.3077x over previous
//
#include <hip/hip_runtime.h>
#include <math.h>
#include <stdint.h>

// Problem dims (fixed by reference)
constexpr int Lz  = 4;
constexpr int Bb  = 128;
constexpr int STd = 512;
constexpr int Dd  = 1536;   // IN + CTX + ST
constexpr int Rr  = 256;
constexpr int Cc  = 256;

typedef __bf16 bf16x8 __attribute__((ext_vector_type(8)));
typedef float  f32x4  __attribute__((ext_vector_type(4)));

__device__ __forceinline__ float sigmoidf_(float v) { return 1.0f / (1.0f + expf(-v)); }

// pack two f32 -> dword of 2 bf16 (round-half-up via +0x8000, then v_perm high halves)
__device__ __forceinline__ uint32_t pkbf16(float a, float b) {
    uint32_t ua = __float_as_uint(a) + 0x8000u;
    uint32_t ub = __float_as_uint(b) + 0x8000u;
    return __builtin_amdgcn_perm(ub, ua, 0x07060302u);  // lo16=bf16(a), hi16=bf16(b)
}
__device__ __forceinline__ uint4 cvt8(const float4 lo, const float4 hi) {
    uint4 r;
    r.x = pkbf16(lo.x, lo.y); r.y = pkbf16(lo.z, lo.w);
    r.z = pkbf16(hi.x, hi.y); r.w = pkbf16(hi.z, hi.w);
    return r;
}

// ============================================================================
// Phase 1: gated state update via bf16 MFMA, depth-2 register prefetch.
// out tile: 32 (b) x 32 (o); 3 weight arrays share the A-fragment.
// LDS fragment-ordered (16B/thread slots), zero-conflict linear ds ops.
// ============================================================================
__global__ __launch_bounds__(256) void k_gate(
    const float* __restrict__ x, const float* __restrict__ c, const float* __restrict__ h,
    const float* __restrict__ phi_w, const float* __restrict__ phi_b,
    const float* __restrict__ alpha_w, const float* __restrict__ alpha_b,
    const float* __restrict__ beta_w, const float* __restrict__ beta_b,
    float* __restrict__ h_new)
{
    __shared__ uint32_t lds[4096];  // A: [0,1024) uints ; B arr a: [1024*(1+a), +1024)

    const int l  = blockIdx.z;
    const int b0 = blockIdx.y * 32;
    const int o0 = blockIdx.x * 32;
    const int t  = threadIdx.x;

    const int rowblk = t >> 7;
    const int kstep  = (t >> 6) & 1;
    const int ls     = t & 63;
    const int mrow   = (rowblk << 4) | (ls & 15);
    const int kd     = kstep * 32 + ((ls >> 4) << 3);
    const int slot_u = t * 4;

    const float* wrow0 = phi_w   + (size_t)(l * STd + o0 + mrow) * Dd + kd;
    const float* wrow1 = alpha_w + (size_t)(l * STd + o0 + mrow) * Dd + kd;
    const float* wrow2 = beta_w  + (size_t)(l * STd + o0 + mrow) * Dd + kd;

    const float* abase0 = x + (size_t)(b0 + mrow) * 512 + kd;
    const float* abase1 = c + (size_t)(b0 + mrow) * 512 + kd - 512;
    const float* abase2 = h + (size_t)(l * Bb + b0 + mrow) * 512 + kd - 1024;

    // depth-2 staging registers
    float4 paA0, paA1, pbA00, pbA01, pbA10, pbA11, pbA20, pbA21;
    float4 paB0, paB1, pbB00, pbB01, pbB10, pbB11, pbB20, pbB21;

    auto issueA = [&](int kk) {
        const float* p = (kk < 512 ? abase0 : (kk < 1024 ? abase1 : abase2)) + kk;
        paA0 = *(const float4*)p;  paA1 = *(const float4*)(p + 4);
        pbA00 = *(const float4*)(wrow0 + kk); pbA01 = *(const float4*)(wrow0 + kk + 4);
        pbA10 = *(const float4*)(wrow1 + kk); pbA11 = *(const float4*)(wrow1 + kk + 4);
        pbA20 = *(const float4*)(wrow2 + kk); pbA21 = *(const float4*)(wrow2 + kk + 4);
    };
    auto issueB = [&](int kk) {
        const float* p = (kk < 512 ? abase0 : (kk < 1024 ? abase1 : abase2)) + kk;
        paB0 = *(const float4*)p;  paB1 = *(const float4*)(p + 4);
        pbB00 = *(const float4*)(wrow0 + kk); pbB01 = *(const float4*)(wrow0 + kk + 4);
        pbB10 = *(const float4*)(wrow1 + kk); pbB11 = *(const float4*)(wrow1 + kk + 4);
        pbB20 = *(const float4*)(wrow2 + kk); pbB21 = *(const float4*)(wrow2 + kk + 4);
    };

    const int lane = t & 63;
    const int w    = t >> 6;
    const int m    = w >> 1;      // A 16-row block
    const int n    = w & 1;       // B 16-col block

    f32x4 acc[3] = {};

    auto mfma_step = [&]() {
        #pragma unroll
        for (int ks = 0; ks < 2; ++ks) {
            bf16x8 af  = *(bf16x8*)&lds[((m * 2 + ks) * 64 + lane) * 4];
            bf16x8 bf0 = *(bf16x8*)&lds[1024 + ((n * 2 + ks) * 64 + lane) * 4];
            bf16x8 bf1 = *(bf16x8*)&lds[2048 + ((n * 2 + ks) * 64 + lane) * 4];
            bf16x8 bf2 = *(bf16x8*)&lds[3072 + ((n * 2 + ks) * 64 + lane) * 4];
            acc[0] = __builtin_amdgcn_mfma_f32_16x16x32_bf16(af, bf0, acc[0], 0, 0, 0);
            acc[1] = __builtin_amdgcn_mfma_f32_16x16x32_bf16(af, bf1, acc[1], 0, 0, 0);
            acc[2] = __builtin_amdgcn_mfma_f32_16x16x32_bf16(af, bf2, acc[2], 0, 0, 0);
        }
    };

    issueA(0);
    issueB(64);
    for (int kk = 0; kk < Dd; kk += 128) {
        // even phase: consume bufA
        *(uint4*)&lds[slot_u]        = cvt8(paA0, paA1);
        *(uint4*)&lds[1024 + slot_u] = cvt8(pbA00, pbA01);
        *(uint4*)&lds[2048 + slot_u] = cvt8(pbA10, pbA11);
        *(uint4*)&lds[3072 + slot_u] = cvt8(pbA20, pbA21);
        __syncthreads();
        if (kk + 128 < Dd) issueA(kk + 128);   // in flight across this+next phase
        mfma_step();
        __syncthreads();
        // odd phase: consume bufB
        *(uint4*)&lds[slot_u]        = cvt8(paB0, paB1);
        *(uint4*)&lds[1024 + slot_u] = cvt8(pbB00, pbB01);
        *(uint4*)&lds[2048 + slot_u] = cvt8(pbB10, pbB11);
        *(uint4*)&lds[3072 + slot_u] = cvt8(pbB20, pbB21);
        __syncthreads();
        if (kk + 192 < Dd) issueB(kk + 192);
        mfma_step();
        __syncthreads();
    }

    // epilogue: h_new = sigmoid(alpha)*tanh(phi) + sigmoid(beta)*h
    const int bout = b0 + m * 16 + (lane >> 4) * 4;
    const int ocol = o0 + n * 16 + (lane & 15);
    const float pbias = phi_b[l * STd + ocol];
    const float abias = alpha_b[l * STd + ocol];
    const float bbias = beta_b[l * STd + ocol];
    #pragma unroll
    for (int r = 0; r < 4; ++r) {
        const int b = bout + r;
        float phi = acc[0][r] + pbias;
        float al  = sigmoidf_(acc[1][r] + abias);
        float be  = sigmoidf_(acc[2][r] + bbias);
        float ho  = h[(size_t)(l * Bb + b) * STd + ocol];
        h_new[(size_t)(l * Bb + b) * STd + ocol] = al * tanhf(phi) + be * ho;
    }
}

// ============================================================================
// Phase 2: u,v projections via bf16 MFMA, depth-2 register prefetch.
// wv = [h_new | x | c]
// ============================================================================
__global__ __launch_bounds__(256) void k_uv(
    const float* __restrict__ x, const float* __restrict__ c,
    const float* __restrict__ h_new,
    const float* __restrict__ u_w, const float* __restrict__ u_b,
    const float* __restrict__ v_w, const float* __restrict__ v_b,
    float* __restrict__ u_out, float* __restrict__ v_out)
{
    __shared__ uint32_t lds[2048];  // A: [0,1024) ; B: [1024,2048)

    const int l   = blockIdx.z;
    const int b0  = blockIdx.y * 32;
    const int n0g = blockIdx.x * 32;   // 0..511 over [u | v]
    const int t   = threadIdx.x;

    const float* W; const float* bias; float* out; int o_base;
    if (n0g < Rr) { W = u_w; bias = u_b; out = u_out; o_base = n0g; }
    else          { W = v_w; bias = v_b; out = v_out; o_base = n0g - Rr; }

    const int rowblk = t >> 7;
    const int kstep  = (t >> 6) & 1;
    const int ls     = t & 63;
    const int mrow   = (rowblk << 4) | (ls & 15);
    const int kd     = kstep * 32 + ((ls >> 4) << 3);
    const int slot_u = t * 4;

    const float* wrow = W + (size_t)(l * Rr + o_base + mrow) * Dd + kd;
    const float* abase0 = h_new + (size_t)(l * Bb + b0 + mrow) * 512 + kd;
    const float* abase1 = x + (size_t)(b0 + mrow) * 512 + kd - 512;
    const float* abase2 = c + (size_t)(b0 + mrow) * 512 + kd - 1024;

    float4 paA0, paA1, pbA0, pbA1;
    float4 paB0, paB1, pbB0, pbB1;

    auto issueA = [&](int kk) {
        const float* p = (kk < 512 ? abase0 : (kk < 1024 ? abase1 : abase2)) + kk;
        paA0 = *(const float4*)p;  paA1 = *(const float4*)(p + 4);
        pbA0 = *(const float4*)(wrow + kk); pbA1 = *(const float4*)(wrow + kk + 4);
    };
    auto issueB = [&](int kk) {
        const float* p = (kk < 512 ? abase0 : (kk < 1024 ? abase1 : abase2)) + kk;
        paB0 = *(const float4*)p;  paB1 = *(const float4*)(p + 4);
        pbB0 = *(const float4*)(wrow + kk); pbB1 = *(const float4*)(wrow + kk + 4);
    };

    const int lane = t & 63;
    const int w    = t >> 6;
    const int m    = w >> 1;
    const int n    = w & 1;

    f32x4 acc = {};

    auto mfma_step = [&]() {
        #pragma unroll
        for (int ks = 0; ks < 2; ++ks) {
            bf16x8 af = *(bf16x8*)&lds[((m * 2 + ks) * 64 + lane) * 4];
            bf16x8 bf = *(bf16x8*)&lds[1024 + ((n * 2 + ks) * 64 + lane) * 4];
            acc = __builtin_amdgcn_mfma_f32_16x16x32_bf16(af, bf, acc, 0, 0, 0);
        }
    };

    issueA(0);
    issueB(64);
    for (int kk = 0; kk < Dd; kk += 128) {
        *(uint4*)&lds[slot_u]        = cvt8(paA0, paA1);
        *(uint4*)&lds[1024 + slot_u] = cvt8(pbA0, pbA1);
        __syncthreads();
        if (kk + 128 < Dd) issueA(kk + 128);
        mfma_step();
        __syncthreads();
        *(uint4*)&lds[slot_u]        = cvt8(paB0, paB1);
        *(uint4*)&lds[1024 + slot_u] = cvt8(pbB0, pbB1);
        __syncthreads();
        if (kk + 192 < Dd) issueB(kk + 192);
        mfma_step();
        __syncthreads();
    }

    const int bout = b0 + m * 16 + (lane >> 4) * 4;
    const int ocol = o_base + n * 16 + (lane & 15);
    const float bv = bias[l * Rr + ocol];
    #pragma unroll
    for (int r = 0; r < 4; ++r) {
        out[(size_t)(l * Bb + bout + r) * Rr + ocol] = acc[r] + bv;
    }
}

// ============================================================================
// Phase 3: EMA memory write. Explicit load hoisting (12 independent loads in
// flight before first use) + nontemporal stores (M_new never re-read; keep L3
// for the M read stream so it stays replay-resident).
// ============================================================================
__global__ __launch_bounds__(256) void k_mupd(
    const float4* __restrict__ M, const float* __restrict__ u, const float4* __restrict__ v,
    const float* __restrict__ gl, const float* __restrict__ el,
    float4* __restrict__ Mout)
{
    const int t = blockIdx.x * 256 + threadIdx.x;   // over B*R*C/4
    const int c4 = t & 63;              // C/4 = 64
    const int r  = (t >> 6) & 255;
    const int b  = t >> 14;
    constexpr int strideL = Bb * Rr * Cc / 4;       // float4 per level

    const float4 m0 = M[0 * strideL + t];
    const float4 m1 = M[1 * strideL + t];
    const float4 m2 = M[2 * strideL + t];
    const float4 m3 = M[3 * strideL + t];

    const int vbase = b * (Cc / 4) + c4;
    constexpr int vstride = Bb * (Cc / 4);
    const float4 v0 = v[0 * vstride + vbase];
    const float4 v1 = v[1 * vstride + vbase];
    const float4 v2 = v[2 * vstride + vbase];
    const float4 v3 = v[3 * vstride + vbase];

    const int ubase = b * Rr + r;
    constexpr int ustride = Bb * Rr;
    const float u0 = u[0 * ustride + ubase];
    const float u1 = u[1 * ustride + ubase];
    const float u2 = u[2 * ustride + ubase];
    const float u3 = u[3 * ustride + ubase];

    const float g0 = sigmoidf_(gl[0]), g1 = sigmoidf_(gl[1]);
    const float g2 = sigmoidf_(gl[2]), g3 = sigmoidf_(gl[3]);
    const float e0 = sigmoidf_(el[0]), e1 = sigmoidf_(el[1]);
    const float e2 = sigmoidf_(el[2]), e3 = sigmoidf_(el[3]);

    auto emit = [&](int l, const float4& mc, const float4& mu, const float4& md,
                    float uu, const float4& vv, float g, float e) {
        f32x4 o;
        o[0] = (1.0f - g) * mc.x + g * 0.5f * (mu.x + md.x) + e * uu * vv.x;
        o[1] = (1.0f - g) * mc.y + g * 0.5f * (mu.y + md.y) + e * uu * vv.y;
        o[2] = (1.0f - g) * mc.z + g * 0.5f * (mu.z + md.z) + e * uu * vv.z;
        o[3] = (1.0f - g) * mc.w + g * 0.5f * (mu.w + md.w) + e * uu * vv.w;
        __builtin_nontemporal_store(o, (f32x4*)&Mout[l * strideL + t]);
    };

    emit(0, m0, m0, m1, u0, v0, g0, e0);
    emit(1, m1, m0, m2, u1, v1, g1, e1);
    emit(2, m2, m1, m3, u2, v2, g2, e2);
    emit(3, m3, m2, m3, u3, v3, g3, e3);
}

extern "C" void kernel_launch(void* const* d_in, const int* in_sizes, int n_in,
                              void* d_out, int out_size, void* d_ws, size_t ws_size,
                              hipStream_t stream) {
    const float* x       = (const float*)d_in[0];
    const float* c       = (const float*)d_in[1];
    const float* h       = (const float*)d_in[2];
    const float* M       = (const float*)d_in[3];
    const float* phi_w   = (const float*)d_in[4];
    const float* phi_b   = (const float*)d_in[5];
    const float* alpha_w = (const float*)d_in[6];
    const float* alpha_b = (const float*)d_in[7];
    const float* beta_w  = (const float*)d_in[8];
    const float* beta_b  = (const float*)d_in[9];
    const float* u_w     = (const float*)d_in[10];
    const float* u_b     = (const float*)d_in[11];
    const float* v_w     = (const float*)d_in[12];
    const float* v_b     = (const float*)d_in[13];
    const float* gl      = (const float*)d_in[14];
    const float* el      = (const float*)d_in[15];

    float* out   = (float*)d_out;
    float* h_new = out;                          // L*B*ST
    float* M_new = out + Lz * Bb * STd;          // L*B*R*C

    float* u = (float*)d_ws;                     // L*B*R
    float* v = u + Lz * Bb * Rr;                 // L*B*C

    k_gate<<<dim3(STd / 32, Bb / 32, Lz), 256, 0, stream>>>(
        x, c, h, phi_w, phi_b, alpha_w, alpha_b, beta_w, beta_b, h_new);
    k_uv<<<dim3((Rr + Cc) / 32, Bb / 32, Lz), 256, 0, stream>>>(
        x, c, h_new, u_w, u_b, v_w, v_b, u, v);
    k_mupd<<<(Bb * Rr * Cc / 4) / 256, 256, 0, stream>>>(
        (const float4*)M, u, (const float4*)v, gl, el, (float4*)M_new);
}

// Round 4
// 89.698 us; speedup vs baseline: 3.4466x; 1.0138x over previous
//
#include <hip/hip_runtime.h>
#include <math.h>
#include <stdint.h>

// Problem dims (fixed by reference)
constexpr int Lz  = 4;
constexpr int Bb  = 128;
constexpr int STd = 512;
constexpr int Dd  = 1536;   // IN + CTX + ST
constexpr int Rr  = 256;
constexpr int Cc  = 256;

typedef __bf16 bf16x8 __attribute__((ext_vector_type(8)));
typedef float  f32x4  __attribute__((ext_vector_type(4)));

__device__ __forceinline__ float sigmoidf_(float v) { return 1.0f / (1.0f + expf(-v)); }

// pack two f32 -> dword of 2 bf16 (round-half-up via +0x8000, then v_perm high halves)
__device__ __forceinline__ uint32_t pkbf16(float a, float b) {
    uint32_t ua = __float_as_uint(a) + 0x8000u;
    uint32_t ub = __float_as_uint(b) + 0x8000u;
    return __builtin_amdgcn_perm(ub, ua, 0x07060302u);  // lo16=bf16(a), hi16=bf16(b)
}
__device__ __forceinline__ uint4 cvt8(const float4 lo, const float4 hi) {
    uint4 r;
    r.x = pkbf16(lo.x, lo.y); r.y = pkbf16(lo.z, lo.w);
    r.z = pkbf16(hi.x, hi.y); r.w = pkbf16(hi.z, hi.w);
    return r;
}

// ============================================================================
// Phase 1: gated state update via bf16 MFMA, depth-2 register prefetch.
// ============================================================================
__global__ __launch_bounds__(256) void k_gate(
    const float* __restrict__ x, const float* __restrict__ c, const float* __restrict__ h,
    const float* __restrict__ phi_w, const float* __restrict__ phi_b,
    const float* __restrict__ alpha_w, const float* __restrict__ alpha_b,
    const float* __restrict__ beta_w, const float* __restrict__ beta_b,
    float* __restrict__ h_new)
{
    __shared__ uint32_t lds[4096];  // A: [0,1024) uints ; B arr a: [1024*(1+a), +1024)

    const int l  = blockIdx.z;
    const int b0 = blockIdx.y * 32;
    const int o0 = blockIdx.x * 32;
    const int t  = threadIdx.x;

    const int rowblk = t >> 7;
    const int kstep  = (t >> 6) & 1;
    const int ls     = t & 63;
    const int mrow   = (rowblk << 4) | (ls & 15);
    const int kd     = kstep * 32 + ((ls >> 4) << 3);
    const int slot_u = t * 4;

    const float* wrow0 = phi_w   + (size_t)(l * STd + o0 + mrow) * Dd + kd;
    const float* wrow1 = alpha_w + (size_t)(l * STd + o0 + mrow) * Dd + kd;
    const float* wrow2 = beta_w  + (size_t)(l * STd + o0 + mrow) * Dd + kd;

    const float* abase0 = x + (size_t)(b0 + mrow) * 512 + kd;
    const float* abase1 = c + (size_t)(b0 + mrow) * 512 + kd - 512;
    const float* abase2 = h + (size_t)(l * Bb + b0 + mrow) * 512 + kd - 1024;

    float4 paA0, paA1, pbA00, pbA01, pbA10, pbA11, pbA20, pbA21;
    float4 paB0, paB1, pbB00, pbB01, pbB10, pbB11, pbB20, pbB21;

    auto issueA = [&](int kk) {
        const float* p = (kk < 512 ? abase0 : (kk < 1024 ? abase1 : abase2)) + kk;
        paA0 = *(const float4*)p;  paA1 = *(const float4*)(p + 4);
        pbA00 = *(const float4*)(wrow0 + kk); pbA01 = *(const float4*)(wrow0 + kk + 4);
        pbA10 = *(const float4*)(wrow1 + kk); pbA11 = *(const float4*)(wrow1 + kk + 4);
        pbA20 = *(const float4*)(wrow2 + kk); pbA21 = *(const float4*)(wrow2 + kk + 4);
    };
    auto issueB = [&](int kk) {
        const float* p = (kk < 512 ? abase0 : (kk < 1024 ? abase1 : abase2)) + kk;
        paB0 = *(const float4*)p;  paB1 = *(const float4*)(p + 4);
        pbB00 = *(const float4*)(wrow0 + kk); pbB01 = *(const float4*)(wrow0 + kk + 4);
        pbB10 = *(const float4*)(wrow1 + kk); pbB11 = *(const float4*)(wrow1 + kk + 4);
        pbB20 = *(const float4*)(wrow2 + kk); pbB21 = *(const float4*)(wrow2 + kk + 4);
    };

    const int lane = t & 63;
    const int w    = t >> 6;
    const int m    = w >> 1;      // A 16-row block
    const int n    = w & 1;       // B 16-col block

    f32x4 acc[3] = {};

    auto mfma_step = [&]() {
        #pragma unroll
        for (int ks = 0; ks < 2; ++ks) {
            bf16x8 af  = *(bf16x8*)&lds[((m * 2 + ks) * 64 + lane) * 4];
            bf16x8 bf0 = *(bf16x8*)&lds[1024 + ((n * 2 + ks) * 64 + lane) * 4];
            bf16x8 bf1 = *(bf16x8*)&lds[2048 + ((n * 2 + ks) * 64 + lane) * 4];
            bf16x8 bf2 = *(bf16x8*)&lds[3072 + ((n * 2 + ks) * 64 + lane) * 4];
            acc[0] = __builtin_amdgcn_mfma_f32_16x16x32_bf16(af, bf0, acc[0], 0, 0, 0);
            acc[1] = __builtin_amdgcn_mfma_f32_16x16x32_bf16(af, bf1, acc[1], 0, 0, 0);
            acc[2] = __builtin_amdgcn_mfma_f32_16x16x32_bf16(af, bf2, acc[2], 0, 0, 0);
        }
    };

    issueA(0);
    issueB(64);
    for (int kk = 0; kk < Dd; kk += 128) {
        *(uint4*)&lds[slot_u]        = cvt8(paA0, paA1);
        *(uint4*)&lds[1024 + slot_u] = cvt8(pbA00, pbA01);
        *(uint4*)&lds[2048 + slot_u] = cvt8(pbA10, pbA11);
        *(uint4*)&lds[3072 + slot_u] = cvt8(pbA20, pbA21);
        __syncthreads();
        if (kk + 128 < Dd) issueA(kk + 128);
        mfma_step();
        __syncthreads();
        *(uint4*)&lds[slot_u]        = cvt8(paB0, paB1);
        *(uint4*)&lds[1024 + slot_u] = cvt8(pbB00, pbB01);
        *(uint4*)&lds[2048 + slot_u] = cvt8(pbB10, pbB11);
        *(uint4*)&lds[3072 + slot_u] = cvt8(pbB20, pbB21);
        __syncthreads();
        if (kk + 192 < Dd) issueB(kk + 192);
        mfma_step();
        __syncthreads();
    }

    const int bout = b0 + m * 16 + (lane >> 4) * 4;
    const int ocol = o0 + n * 16 + (lane & 15);
    const float pbias = phi_b[l * STd + ocol];
    const float abias = alpha_b[l * STd + ocol];
    const float bbias = beta_b[l * STd + ocol];
    #pragma unroll
    for (int r = 0; r < 4; ++r) {
        const int b = bout + r;
        float phi = acc[0][r] + pbias;
        float al  = sigmoidf_(acc[1][r] + abias);
        float be  = sigmoidf_(acc[2][r] + bbias);
        float ho  = h[(size_t)(l * Bb + b) * STd + ocol];
        h_new[(size_t)(l * Bb + b) * STd + ocol] = al * tanhf(phi) + be * ho;
    }
}

// ============================================================================
// Phase 2: u,v projections via bf16 MFMA, depth-2 register prefetch.
// ============================================================================
__global__ __launch_bounds__(256) void k_uv(
    const float* __restrict__ x, const float* __restrict__ c,
    const float* __restrict__ h_new,
    const float* __restrict__ u_w, const float* __restrict__ u_b,
    const float* __restrict__ v_w, const float* __restrict__ v_b,
    float* __restrict__ u_out, float* __restrict__ v_out)
{
    __shared__ uint32_t lds[2048];  // A: [0,1024) ; B: [1024,2048)

    const int l   = blockIdx.z;
    const int b0  = blockIdx.y * 32;
    const int n0g = blockIdx.x * 32;   // 0..511 over [u | v]
    const int t   = threadIdx.x;

    const float* W; const float* bias; float* out; int o_base;
    if (n0g < Rr) { W = u_w; bias = u_b; out = u_out; o_base = n0g; }
    else          { W = v_w; bias = v_b; out = v_out; o_base = n0g - Rr; }

    const int rowblk = t >> 7;
    const int kstep  = (t >> 6) & 1;
    const int ls     = t & 63;
    const int mrow   = (rowblk << 4) | (ls & 15);
    const int kd     = kstep * 32 + ((ls >> 4) << 3);
    const int slot_u = t * 4;

    const float* wrow = W + (size_t)(l * Rr + o_base + mrow) * Dd + kd;
    const float* abase0 = h_new + (size_t)(l * Bb + b0 + mrow) * 512 + kd;
    const float* abase1 = x + (size_t)(b0 + mrow) * 512 + kd - 512;
    const float* abase2 = c + (size_t)(b0 + mrow) * 512 + kd - 1024;

    float4 paA0, paA1, pbA0, pbA1;
    float4 paB0, paB1, pbB0, pbB1;

    auto issueA = [&](int kk) {
        const float* p = (kk < 512 ? abase0 : (kk < 1024 ? abase1 : abase2)) + kk;
        paA0 = *(const float4*)p;  paA1 = *(const float4*)(p + 4);
        pbA0 = *(const float4*)(wrow + kk); pbA1 = *(const float4*)(wrow + kk + 4);
    };
    auto issueB = [&](int kk) {
        const float* p = (kk < 512 ? abase0 : (kk < 1024 ? abase1 : abase2)) + kk;
        paB0 = *(const float4*)p;  paB1 = *(const float4*)(p + 4);
        pbB0 = *(const float4*)(wrow + kk); pbB1 = *(const float4*)(wrow + kk + 4);
    };

    const int lane = t & 63;
    const int w    = t >> 6;
    const int m    = w >> 1;
    const int n    = w & 1;

    f32x4 acc = {};

    auto mfma_step = [&]() {
        #pragma unroll
        for (int ks = 0; ks < 2; ++ks) {
            bf16x8 af = *(bf16x8*)&lds[((m * 2 + ks) * 64 + lane) * 4];
            bf16x8 bf = *(bf16x8*)&lds[1024 + ((n * 2 + ks) * 64 + lane) * 4];
            acc = __builtin_amdgcn_mfma_f32_16x16x32_bf16(af, bf, acc, 0, 0, 0);
        }
    };

    issueA(0);
    issueB(64);
    for (int kk = 0; kk < Dd; kk += 128) {
        *(uint4*)&lds[slot_u]        = cvt8(paA0, paA1);
        *(uint4*)&lds[1024 + slot_u] = cvt8(pbA0, pbA1);
        __syncthreads();
        if (kk + 128 < Dd) issueA(kk + 128);
        mfma_step();
        __syncthreads();
        *(uint4*)&lds[slot_u]        = cvt8(paB0, paB1);
        *(uint4*)&lds[1024 + slot_u] = cvt8(pbB0, pbB1);
        __syncthreads();
        if (kk + 192 < Dd) issueB(kk + 192);
        mfma_step();
        __syncthreads();
    }

    const int bout = b0 + m * 16 + (lane >> 4) * 4;
    const int ocol = o_base + n * 16 + (lane & 15);
    const float bv = bias[l * Rr + ocol];
    #pragma unroll
    for (int r = 0; r < 4; ++r) {
        out[(size_t)(l * Bb + bout + r) * Rr + ocol] = acc[r] + bv;
    }
}

// ============================================================================
// Phase 3: EMA memory write — persistent chunked blocks.
// 1024 blocks; block owns 2048 consecutive float4 sites per level (32 KB/stream,
// all within one batch b). u/v staged (LDS / regs) once per block; inner loop
// is 8 iterations of {prefetch next 4 M-vectors, compute, 4 NT stores}.
// ============================================================================
__global__ __launch_bounds__(256, 4) void k_mupd(
    const float4* __restrict__ M, const float* __restrict__ u, const float4* __restrict__ v,
    const float* __restrict__ gl, const float* __restrict__ el,
    float4* __restrict__ Mout)
{
    constexpr int SL      = Bb * Rr * Cc / 4;   // float4 per level
    constexpr int ustride = Bb * Rr;
    constexpr int vstride = Bb * (Cc / 4);
    constexpr int CH      = 2048;               // float4 sites per block per level

    __shared__ float su[4][32];   // u values for this block's 32 r rows, 4 levels

    const int bid = blockIdx.x;
    const int tid = threadIdx.x;
    const int b     = bid >> 3;            // 8 blocks per batch index
    const int rbase = (bid & 7) * 32;
    const int c4    = tid & 63;
    const int w     = tid >> 6;

    if (tid < 128) {
        int l = tid >> 5, rl = tid & 31;
        su[l][rl] = u[l * ustride + b * Rr + rbase + rl];
    }

    // v depends only on (l, b, c4) — constant per thread; keep in registers
    const int vb = b * (Cc / 4) + c4;
    const float4 v0 = v[0 * vstride + vb];
    const float4 v1 = v[1 * vstride + vb];
    const float4 v2 = v[2 * vstride + vb];
    const float4 v3 = v[3 * vstride + vb];

    // uniform gate scalars (uniform address -> s_load path)
    const float g0 = sigmoidf_(gl[0]), g1 = sigmoidf_(gl[1]);
    const float g2 = sigmoidf_(gl[2]), g3 = sigmoidf_(gl[3]);
    const float e0 = sigmoidf_(el[0]), e1 = sigmoidf_(el[1]);
    const float e2 = sigmoidf_(el[2]), e3 = sigmoidf_(el[3]);

    __syncthreads();

    const int base = bid * CH + tid;

    float4 mc0 = M[0 * SL + base];
    float4 mc1 = M[1 * SL + base];
    float4 mc2 = M[2 * SL + base];
    float4 mc3 = M[3 * SL + base];

    #pragma unroll 1
    for (int it = 0; it < CH / 256; ++it) {
        const int s = base + it * 256;
        float4 mn0, mn1, mn2, mn3;
        if (it + 1 < CH / 256) {
            mn0 = M[0 * SL + s + 256];
            mn1 = M[1 * SL + s + 256];
            mn2 = M[2 * SL + s + 256];
            mn3 = M[3 * SL + s + 256];
        }

        const int rl = it * 4 + w;
        const float u0 = su[0][rl], u1 = su[1][rl], u2 = su[2][rl], u3 = su[3][rl];

        f32x4 o0, o1, o2, o3;
        o0[0] = (1.0f-g0)*mc0.x + g0*0.5f*(mc0.x+mc1.x) + e0*u0*v0.x;
        o0[1] = (1.0f-g0)*mc0.y + g0*0.5f*(mc0.y+mc1.y) + e0*u0*v0.y;
        o0[2] = (1.0f-g0)*mc0.z + g0*0.5f*(mc0.z+mc1.z) + e0*u0*v0.z;
        o0[3] = (1.0f-g0)*mc0.w + g0*0.5f*(mc0.w+mc1.w) + e0*u0*v0.w;

        o1[0] = (1.0f-g1)*mc1.x + g1*0.5f*(mc0.x+mc2.x) + e1*u1*v1.x;
        o1[1] = (1.0f-g1)*mc1.y + g1*0.5f*(mc0.y+mc2.y) + e1*u1*v1.y;
        o1[2] = (1.0f-g1)*mc1.z + g1*0.5f*(mc0.z+mc2.z) + e1*u1*v1.z;
        o1[3] = (1.0f-g1)*mc1.w + g1*0.5f*(mc0.w+mc2.w) + e1*u1*v1.w;

        o2[0] = (1.0f-g2)*mc2.x + g2*0.5f*(mc1.x+mc3.x) + e2*u2*v2.x;
        o2[1] = (1.0f-g2)*mc2.y + g2*0.5f*(mc1.y+mc3.y) + e2*u2*v2.y;
        o2[2] = (1.0f-g2)*mc2.z + g2*0.5f*(mc1.z+mc3.z) + e2*u2*v2.z;
        o2[3] = (1.0f-g2)*mc2.w + g2*0.5f*(mc1.w+mc3.w) + e2*u2*v2.w;

        o3[0] = (1.0f-g3)*mc3.x + g3*0.5f*(mc2.x+mc3.x) + e3*u3*v3.x;
        o3[1] = (1.0f-g3)*mc3.y + g3*0.5f*(mc2.y+mc3.y) + e3*u3*v3.y;
        o3[2] = (1.0f-g3)*mc3.z + g3*0.5f*(mc2.z+mc3.z) + e3*u3*v3.z;
        o3[3] = (1.0f-g3)*mc3.w + g3*0.5f*(mc2.w+mc3.w) + e3*u3*v3.w;

        __builtin_nontemporal_store(o0, (f32x4*)&Mout[0 * SL + s]);
        __builtin_nontemporal_store(o1, (f32x4*)&Mout[1 * SL + s]);
        __builtin_nontemporal_store(o2, (f32x4*)&Mout[2 * SL + s]);
        __builtin_nontemporal_store(o3, (f32x4*)&Mout[3 * SL + s]);

        mc0 = mn0; mc1 = mn1; mc2 = mn2; mc3 = mn3;
    }
}

extern "C" void kernel_launch(void* const* d_in, const int* in_sizes, int n_in,
                              void* d_out, int out_size, void* d_ws, size_t ws_size,
                              hipStream_t stream) {
    const float* x       = (const float*)d_in[0];
    const float* c       = (const float*)d_in[1];
    const float* h       = (const float*)d_in[2];
    const float* M       = (const float*)d_in[3];
    const float* phi_w   = (const float*)d_in[4];
    const float* phi_b   = (const float*)d_in[5];
    const float* alpha_w = (const float*)d_in[6];
    const float* alpha_b = (const float*)d_in[7];
    const float* beta_w  = (const float*)d_in[8];
    const float* beta_b  = (const float*)d_in[9];
    const float* u_w     = (const float*)d_in[10];
    const float* u_b     = (const float*)d_in[11];
    const float* v_w     = (const float*)d_in[12];
    const float* v_b     = (const float*)d_in[13];
    const float* gl      = (const float*)d_in[14];
    const float* el      = (const float*)d_in[15];

    float* out   = (float*)d_out;
    float* h_new = out;                          // L*B*ST
    float* M_new = out + Lz * Bb * STd;          // L*B*R*C

    float* u = (float*)d_ws;                     // L*B*R
    float* v = u + Lz * Bb * Rr;                 // L*B*C

    k_gate<<<dim3(STd / 32, Bb / 32, Lz), 256, 0, stream>>>(
        x, c, h, phi_w, phi_b, alpha_w, alpha_b, beta_w, beta_b, h_new);
    k_uv<<<dim3((Rr + Cc) / 32, Bb / 32, Lz), 256, 0, stream>>>(
        x, c, h_new, u_w, u_b, v_w, v_b, u, v);
    // 1024 persistent blocks, 2048 float4 sites per level each
    k_mupd<<<1024, 256, 0, stream>>>(
        (const float4*)M, u, (const float4*)v, gl, el, (float4*)M_new);
}